// Round 9
// baseline (289.197 us; speedup 1.0000x reference)
//
#include <hip/hip_runtime.h>
#include <math.h>

typedef __attribute__((ext_vector_type(8))) short bf16x8;   // 8 bf16 = 4 VGPRs
typedef __attribute__((ext_vector_type(4))) float floatx4;

static __device__ __forceinline__ short f2bf(float f) {
    union { float f; unsigned u; } a; a.f = f;
    unsigned r = a.u + 0x7fffu + ((a.u >> 16) & 1u);   // RNE
    return (short)(r >> 16);
}
static __device__ __forceinline__ float bf2f(short s) {
    union { unsigned u; float f; } c; c.u = ((unsigned)(unsigned short)s) << 16;
    return c.f;
}

// ---------------------------------------------------------------------------
// prep: 16 blocks; block bb:
//   - computes qwk rows [bb*16, bb*16+16) and packs them straight into Bq
//   - packs Wv / Wo rows [bb*16, bb*16+16) into Wvh / Bo (coalesced reads)
// ---------------------------------------------------------------------------
__global__ __launch_bounds__(256) void prep_kernel(
    const float* __restrict__ query,        // [2][256]
    const float* __restrict__ Wk,           // [256][256]
    const float* __restrict__ rpe_bias,     // [9][16]
    const float* __restrict__ attn_scale_w, // [9][16]
    const float* __restrict__ Wv,           // [256][256]
    const float* __restrict__ Wo,           // [256][256]
    float* __restrict__ rpe_exp,            // out [9][16]
    float* __restrict__ rpe_scale,          // out [9][16]
    short* __restrict__ Bq,                 // out [4096]  (MFMA b-frag layout)
    short* __restrict__ Wvh,                // out [65536] (full b-frag pack)
    short* __restrict__ Bo)                 // out [65536]
{
    __shared__ float qn[16 * 33];
    __shared__ float Wt[16][260];
    __shared__ float qwk_s[16][17];
    int tid = threadIdx.x, bb = blockIdx.x;

    for (int i = tid; i < 512; i += 256) {
        int qq  = i >> 8;
        int rem = i & 255;
        int h   = rem >> 5;
        int d   = rem & 31;
        qn[((qq << 3) + h) * 33 + d] = query[i];
    }
    for (int i = tid; i < 16 * 256; i += 256)
        Wt[i >> 8][i & 255] = Wk[bb * 16 * 256 + i];
    __syncthreads();
    if (tid < 16) {
        float s = 0.f;
        #pragma unroll
        for (int d = 0; d < 32; ++d) { float t = qn[tid * 33 + d]; s += t * t; }
        float inv = 1.0f / ((sqrtf(s) + 1e-6f) * sqrtf(32.0f));
        #pragma unroll
        for (int d = 0; d < 32; ++d) qn[tid * 33 + d] *= inv;
    }
    __syncthreads();

    int g  = tid & 15;
    int Dl = tid >> 4;
    int h2 = g & 7;
    float acc = 0.f;
    #pragma unroll
    for (int d = 0; d < 32; ++d)
        acc += qn[g * 33 + d] * Wt[Dl][h2 * 32 + d];
    qwk_s[Dl][g] = acc;
    __syncthreads();

    // Bq pack for this block's 16 k-rows (b-frag: id = kc*512 + lane*8 + j)
    {
        int kl = tid >> 4, gg = tid & 15;
        int k  = bb * 16 + kl;
        int kc = k >> 5, q5 = k & 31, qd = q5 >> 3, j = q5 & 7;
        int lane = qd * 16 + gg;
        Bq[kc * 512 + lane * 8 + j] = f2bf(qwk_s[kl][gg]);
    }

    // Wvh / Bo pack: coalesced row reads (thread = column n)
    for (int kl = 0; kl < 16; ++kl) {
        int k  = bb * 16 + kl;
        int kc = k >> 5, q5 = k & 31, qd = q5 >> 3, j = q5 & 7;
        int n  = tid;
        int gg = n & 15;
        int lane = qd * 16 + gg;
        float vv = Wv[k * 256 + n];
        float vo = Wo[k * 256 + n];
        int nt  = n >> 4;
        Wvh[nt * 4096 + kc * 512 + lane * 8 + j] = f2bf(vv);
        Bo[nt * 4096 + kc * 512 + lane * 8 + j]  = f2bf(vo);
    }

    if (bb == 0 && tid < 144) {
        float r = expf(rpe_bias[tid]);
        rpe_exp[tid]   = r;
        rpe_scale[tid] = r * attn_scale_w[tid];
    }
}

// ---------------------------------------------------------------------------
// Kernel A: per-pixel V = X.Wv (bf16) and ces = exp(X.qwk) (fp32), no halo.
// Block = 64 pixels, 256 threads (4 waves, wave = 16-pixel m-tile).
// LDS 33.8 KB -> 4 blocks/CU. B-frags stream from L2 with immediate use
// (compiler rematerialization is harmless here by design).
// Results transposed through the dead X-stage for coalesced 16B stores.
// ---------------------------------------------------------------------------
#define XROWA 264
__global__ __launch_bounds__(256) void va_kernel(
    const float* __restrict__ x,          // [131072][256] fp32
    const short* __restrict__ Bq,         // [4096]
    const short* __restrict__ Wvh,        // [65536]
    short* __restrict__ V,                // out [131072][256] bf16
    float* __restrict__ cesg)             // out [131072][16] fp32
{
    __shared__ short XA[64 * XROWA];      // 33792 B; X-stage, then V-stage
    int tid  = threadIdx.x;
    int lane = tid & 63, wv = tid >> 6;   // 4 waves
    int m16  = lane & 15, quad = lane >> 4;
    size_t p0 = (size_t)blockIdx.x * 64;

    // stage 64 pixel rows, coalesced
    #pragma unroll
    for (int i = 0; i < 8; ++i) {
        int it  = tid + i * 256;          // 0..2047 = 64 rows x 32 chunks
        int row = it >> 5, l = it & 31;
        const float* xp = x + (p0 + row) * 256 + l * 8;
        float4 f0 = *(const float4*)xp;
        float4 f1 = *(const float4*)(xp + 4);
        bf16x8 s;
        s[0] = f2bf(f0.x); s[1] = f2bf(f0.y); s[2] = f2bf(f0.z); s[3] = f2bf(f0.w);
        s[4] = f2bf(f1.x); s[5] = f2bf(f1.y); s[6] = f2bf(f1.z); s[7] = f2bf(f1.w);
        *(bf16x8*)&XA[row * XROWA + l * 8] = s;
    }
    __syncthreads();

    // A-frag preload (wave's own 16 rows); LDS writes below can't alias-remat
    bf16x8 Arow[8];
    const short* xrow = &XA[(wv * 16 + m16) * XROWA + quad * 8];
    #pragma unroll
    for (int kc = 0; kc < 8; ++kc)
        Arow[kc] = *(const bf16x8*)(xrow + kc * 32);
    __syncthreads();                      // all frag reads done -> XA reusable

    // ces = exp(X . qwk)
    {
        floatx4 acc = (floatx4){0.f, 0.f, 0.f, 0.f};
        const short* bq = Bq + lane * 8;
        #pragma unroll
        for (int kc = 0; kc < 8; ++kc)
            acc = __builtin_amdgcn_mfma_f32_16x16x32_bf16(
                      Arow[kc], *(const bf16x8*)(bq + kc * 512), acc, 0, 0, 0);
        #pragma unroll
        for (int r = 0; r < 4; ++r)
            cesg[(p0 + wv * 16 + quad * 4 + r) * 16 + m16] = expf(acc[r]);
    }

    // V = X . Wv : 16 n-tiles, results into V-stage (over dead XA rows)
    #pragma unroll 4
    for (int nt = 0; nt < 16; ++nt) {
        floatx4 acc = (floatx4){0.f, 0.f, 0.f, 0.f};
        const short* bp = Wvh + nt * 4096 + lane * 8;
        #pragma unroll
        for (int kc = 0; kc < 8; ++kc)
            acc = __builtin_amdgcn_mfma_f32_16x16x32_bf16(
                      Arow[kc], *(const bf16x8*)(bp + kc * 512), acc, 0, 0, 0);
        #pragma unroll
        for (int r = 0; r < 4; ++r)
            XA[(wv * 16 + quad * 4 + r) * XROWA + nt * 16 + m16] = f2bf(acc[r]);
    }
    __syncthreads();

    // coalesced bf16x8 V stores
    #pragma unroll
    for (int i = 0; i < 8; ++i) {
        int it  = tid + i * 256;
        int row = it >> 5, l = it & 31;
        *(bf16x8*)&V[(p0 + row) * 256 + l * 8] =
            *(const bf16x8*)&XA[row * XROWA + l * 8];
    }
}

// ---------------------------------------------------------------------------
// Kernel B: softmax-stencil + output projection. Block = 16 output pixels
// (half an output row), 512 thr. ces/V read from global (L2/L3-resident).
// LDS 14 KB, 3 barriers -> high occupancy; OOB window taps get weight 0 and
// a clamped (safe) address.
// ---------------------------------------------------------------------------
#define OROW 264
__global__ __launch_bounds__(512) void qb_kernel(
    const float* __restrict__ cesg,       // [131072][16]
    const short* __restrict__ V,          // [131072][256] bf16
    const float* __restrict__ rpe_exp,    // [9][16]
    const float* __restrict__ rpe_scale,  // [9][16]
    const short* __restrict__ Bo,         // [65536]
    float* __restrict__ out)              // [32768][256] fp32
{
    __shared__ short out_tr[16 * OROW];   // 8448 B
    __shared__ float wcoefs[8][9][16];    // 4608 B [h][w][op]
    __shared__ float invden[16][16];      // 1024 B  (total 14080)

    int tid  = threadIdx.x;
    int lane = tid & 63, wv = tid >> 6;
    int m16  = lane & 15, quad = lane >> 4;

    int blk0 = blockIdx.x;
    int blk  = ((blk0 & 7) << 8) | (blk0 >> 3);  // XCD-contiguous, bijective
    int b   = blk >> 6;
    int io  = (blk >> 1) & 31;
    int hf  = blk & 1;
    int i0  = io * 2 - 1;
    int jbase = hf * 32 - 1;

    // ---- P2a: invden ----
    if (tid < 256) {
        int op = tid >> 4, g = tid & 15;
        float den = 0.f;
        #pragma unroll
        for (int w = 0; w < 9; ++w) {
            int ky = w / 3, kx = w - ky * 3;
            int ii = i0 + ky, jj = jbase + 2 * op + kx;
            if ((unsigned)ii < 64u && (unsigned)jj < 64u) {
                size_t pix = ((size_t)((b << 6) + ii) << 6) + jj;
                den = fmaf(rpe_exp[w * 16 + g], cesg[pix * 16 + g], den);
            }
        }
        invden[op][g] = 1.0f / den;
    }
    __syncthreads();

    // ---- P2b: wcoefs[h][w][op] (queries q=0/1 merged; 0 when OOB) ----
    for (int it = tid; it < 1152; it += 512) {
        int op = it / 72, r = it - op * 72;
        int w = r >> 3, h = r & 7;
        int ky = w / 3, kx = w - ky * 3;
        int ii = i0 + ky, jj = jbase + 2 * op + kx;
        float v = 0.f;
        if ((unsigned)ii < 64u && (unsigned)jj < 64u) {
            size_t pix = ((size_t)((b << 6) + ii) << 6) + jj;
            v = cesg[pix * 16 + h]     * rpe_scale[w * 16 + h]     * invden[op][h] +
                cesg[pix * 16 + 8 + h] * rpe_scale[w * 16 + 8 + h] * invden[op][8 + h];
        }
        wcoefs[h][w][op] = v;
    }
    __syncthreads();

    // ---- P3: stencil on V (global, coalesced 512B rows) -> out_tr ----
    {
        int op = tid >> 5;                // 0..15
        int nc = tid & 31;                // 8-feature chunk
        int h  = nc >> 2;
        float wcv[9];
        #pragma unroll
        for (int w = 0; w < 9; ++w) wcv[w] = wcoefs[h][w][op];

        float o[8];
        #pragma unroll
        for (int j = 0; j < 8; ++j) o[j] = 0.f;
        #pragma unroll
        for (int w = 0; w < 9; ++w) {
            int ky = w / 3, kx = w - ky * 3;
            int ii = i0 + ky, jj = jbase + 2 * op + kx;
            bool valid = ((unsigned)ii < 64u) && ((unsigned)jj < 64u);
            size_t pix = valid ? (((size_t)((b << 6) + ii) << 6) + jj) : 0;
            bf16x8 vv = *(const bf16x8*)&V[pix * 256 + nc * 8];
            #pragma unroll
            for (int j = 0; j < 8; ++j)
                o[j] = fmaf(wcv[w], bf2f(vv[j]), o[j]);   // wcv==0 when OOB
        }
        bf16x8 ob;
        #pragma unroll
        for (int j = 0; j < 8; ++j) ob[j] = f2bf(o[j]);
        *(bf16x8*)&out_tr[op * OROW + nc * 8] = ob;
    }
    __syncthreads();

    // ---- P5: out = out_tr . Wo (nt pair = wave), write fp32 ----
    {
        floatx4 acc0 = (floatx4){0.f, 0.f, 0.f, 0.f};
        floatx4 acc1 = (floatx4){0.f, 0.f, 0.f, 0.f};
        int nt0 = wv * 2;
        const short* bp = Bo + nt0 * 4096 + lane * 8;
        #pragma unroll
        for (int kc = 0; kc < 8; ++kc) {
            bf16x8 a  = *(const bf16x8*)&out_tr[m16 * OROW + kc * 32 + quad * 8];
            bf16x8 b0 = *(const bf16x8*)(bp + kc * 512);
            bf16x8 b1 = *(const bf16x8*)(bp + 4096 + kc * 512);
            acc0 = __builtin_amdgcn_mfma_f32_16x16x32_bf16(a, b0, acc0, 0, 0, 0);
            acc1 = __builtin_amdgcn_mfma_f32_16x16x32_bf16(a, b1, acc1, 0, 0, 0);
        }
        size_t op0 = (size_t)blk * 16;
        #pragma unroll
        for (int r = 0; r < 4; ++r) {
            out[(op0 + quad * 4 + r) * 256 + nt0 * 16 + m16]       = acc0[r];
            out[(op0 + quad * 4 + r) * 256 + (nt0 + 1) * 16 + m16] = acc1[r];
        }
    }
}

// ---------------------------------------------------------------------------
// workspace layout (floats):
//   [0,144)        rpe_exp        [144,288)     rpe_scale
//   [288,2336)     Bq (4096 bf16) [2336,35104)  Wvh (65536 bf16)
//   [35104,67872)  Bo (65536 bf16)
//   [68608, 68608+16777216)       V  (33554432 bf16 = 64 MiB)
//   [+16777216, +2097152)         ces (131072 x 16 fp32 = 8 MiB)
//   total ~75.8 MB of d_ws
// ---------------------------------------------------------------------------
extern "C" void kernel_launch(void* const* d_in, const int* in_sizes, int n_in,
                              void* d_out, int out_size, void* d_ws, size_t ws_size,
                              hipStream_t stream)
{
    const float* x     = (const float*)d_in[0];
    const float* query = (const float*)d_in[1];
    const float* Wk    = (const float*)d_in[2];
    const float* Wv    = (const float*)d_in[3];
    const float* rpe   = (const float*)d_in[4];
    const float* asw   = (const float*)d_in[5];
    const float* Wo    = (const float*)d_in[6];
    float* out = (float*)d_out;

    float* ws        = (float*)d_ws;
    float* rpe_exp   = ws;
    float* rpe_scale = ws + 144;
    short* Bq        = (short*)(ws + 288);
    short* Wvh       = (short*)(ws + 288 + 2048);
    short* Bo        = (short*)(ws + 288 + 2048 + 32768);
    short* V         = (short*)(ws + 68608);
    float* cesg      = ws + 68608 + 16777216;

    prep_kernel<<<dim3(16), dim3(256), 0, stream>>>(query, Wk, rpe, asw, Wv, Wo,
                                                    rpe_exp, rpe_scale, Bq, Wvh, Bo);
    va_kernel<<<dim3(2048), dim3(256), 0, stream>>>(x, Bq, Wvh, V, cesg);
    qb_kernel<<<dim3(2048), dim3(512), 0, stream>>>(cesg, V, rpe_exp, rpe_scale,
                                                    Bo, out);
}

// Round 10
// 271.957 us; speedup vs baseline: 1.0634x; 1.0634x over previous
//
#include <hip/hip_runtime.h>
#include <math.h>

typedef __attribute__((ext_vector_type(8))) short bf16x8;   // 8 bf16 = 4 VGPRs
typedef __attribute__((ext_vector_type(4))) float floatx4;

static __device__ __forceinline__ short f2bf(float f) {
    union { float f; unsigned u; } a; a.f = f;
    unsigned r = a.u + 0x7fffu + ((a.u >> 16) & 1u);   // RNE
    return (short)(r >> 16);
}
static __device__ __forceinline__ float bf2f(short s) {
    union { unsigned u; float f; } c; c.u = ((unsigned)(unsigned short)s) << 16;
    return c.f;
}

// ---------------------------------------------------------------------------
// prep: 16 blocks; block bb:
//   - computes qwk rows [bb*16, bb*16+16) and packs them straight into Bq
//   - packs Wv / Wo rows [bb*16, bb*16+16) into Wvh / Bo (coalesced reads)
// ---------------------------------------------------------------------------
__global__ __launch_bounds__(256) void prep_kernel(
    const float* __restrict__ query,        // [2][256]
    const float* __restrict__ Wk,           // [256][256]
    const float* __restrict__ rpe_bias,     // [9][16]
    const float* __restrict__ attn_scale_w, // [9][16]
    const float* __restrict__ Wv,           // [256][256]
    const float* __restrict__ Wo,           // [256][256]
    float* __restrict__ rpe_exp,            // out [9][16]
    float* __restrict__ rpe_scale,          // out [9][16]
    short* __restrict__ Bq,                 // out [4096]  (MFMA b-frag layout)
    short* __restrict__ Wvh,                // out [65536] (full b-frag pack)
    short* __restrict__ Bo)                 // out [65536]
{
    __shared__ float qn[16 * 33];
    __shared__ float Wt[16][260];
    __shared__ float qwk_s[16][17];
    int tid = threadIdx.x, bb = blockIdx.x;

    for (int i = tid; i < 512; i += 256) {
        int qq  = i >> 8;
        int rem = i & 255;
        int h   = rem >> 5;
        int d   = rem & 31;
        qn[((qq << 3) + h) * 33 + d] = query[i];
    }
    for (int i = tid; i < 16 * 256; i += 256)
        Wt[i >> 8][i & 255] = Wk[bb * 16 * 256 + i];
    __syncthreads();
    if (tid < 16) {
        float s = 0.f;
        #pragma unroll
        for (int d = 0; d < 32; ++d) { float t = qn[tid * 33 + d]; s += t * t; }
        float inv = 1.0f / ((sqrtf(s) + 1e-6f) * sqrtf(32.0f));
        #pragma unroll
        for (int d = 0; d < 32; ++d) qn[tid * 33 + d] *= inv;
    }
    __syncthreads();

    int g  = tid & 15;
    int Dl = tid >> 4;
    int h2 = g & 7;
    float acc = 0.f;
    #pragma unroll
    for (int d = 0; d < 32; ++d)
        acc += qn[g * 33 + d] * Wt[Dl][h2 * 32 + d];
    qwk_s[Dl][g] = acc;
    __syncthreads();

    // Bq pack for this block's 16 k-rows (b-frag: id = kc*512 + lane*8 + j)
    {
        int kl = tid >> 4, gg = tid & 15;
        int k  = bb * 16 + kl;
        int kc = k >> 5, q5 = k & 31, qd = q5 >> 3, j = q5 & 7;
        int lane = qd * 16 + gg;
        Bq[kc * 512 + lane * 8 + j] = f2bf(qwk_s[kl][gg]);
    }

    // Wvh / Bo pack: coalesced row reads (thread = column n)
    for (int kl = 0; kl < 16; ++kl) {
        int k  = bb * 16 + kl;
        int kc = k >> 5, q5 = k & 31, qd = q5 >> 3, j = q5 & 7;
        int n  = tid;
        int gg = n & 15;
        int lane = qd * 16 + gg;
        float vv = Wv[k * 256 + n];
        float vo = Wo[k * 256 + n];
        int nt  = n >> 4;
        Wvh[nt * 4096 + kc * 512 + lane * 8 + j] = f2bf(vv);
        Bo[nt * 4096 + kc * 512 + lane * 8 + j]  = f2bf(vo);
    }

    if (bb == 0 && tid < 144) {
        float r = expf(rpe_bias[tid]);
        rpe_exp[tid]   = r;
        rpe_scale[tid] = r * attn_scale_w[tid];
    }
}

// ---------------------------------------------------------------------------
// Kernel A (v2): per-pixel V = X.Wv (bf16) and ces = exp(X.qwk), no halo.
// kc-OUTER, B-amortized: wave wv owns n-tiles 4wv..4wv+3; per kc it loads
// 4 B-frags once and MFMAs them against all 4 m-tiles (A from LDS).
// Wvh L2 re-read drops 4x vs round 9 (128 KB/block); B-loads are hidden
// under 16 MFMAs + next-kc prefetch; acc[4][4] static-indexed (64 VGPR).
// Block = 64 pixels, 256 thr, LDS 33.8 KB -> 4 blocks/CU.
// ---------------------------------------------------------------------------
#define XROWA 264
__global__ __launch_bounds__(256, 4) void va_kernel(
    const float* __restrict__ x,          // [131072][256] fp32
    const short* __restrict__ Bq,         // [4096]
    const short* __restrict__ Wvh,        // [65536]
    short* __restrict__ V,                // out [131072][256] bf16
    float* __restrict__ cesg)             // out [131072][16] fp32
{
    __shared__ short XA[64 * XROWA];      // 33792 B; X-stage, then V-stage
    int tid  = threadIdx.x;
    int lane = tid & 63, wv = tid >> 6;   // 4 waves
    int m16  = lane & 15, quad = lane >> 4;
    size_t p0 = (size_t)blockIdx.x * 64;

    // stage 64 pixel rows, coalesced
    #pragma unroll
    for (int i = 0; i < 8; ++i) {
        int it  = tid + i * 256;          // 0..2047 = 64 rows x 32 chunks
        int row = it >> 5, l = it & 31;
        const float* xp = x + (p0 + row) * 256 + l * 8;
        float4 f0 = *(const float4*)xp;
        float4 f1 = *(const float4*)(xp + 4);
        bf16x8 s;
        s[0] = f2bf(f0.x); s[1] = f2bf(f0.y); s[2] = f2bf(f0.z); s[3] = f2bf(f0.w);
        s[4] = f2bf(f1.x); s[5] = f2bf(f1.y); s[6] = f2bf(f1.z); s[7] = f2bf(f1.w);
        *(bf16x8*)&XA[row * XROWA + l * 8] = s;
    }
    __syncthreads();

    // ces = exp(X . qwk) for this wave's m-tile (A from LDS)
    {
        floatx4 acc = (floatx4){0.f, 0.f, 0.f, 0.f};
        const short* bq   = Bq + lane * 8;
        const short* xrow = &XA[(wv * 16 + m16) * XROWA + quad * 8];
        #pragma unroll
        for (int kc = 0; kc < 8; ++kc) {
            bf16x8 a = *(const bf16x8*)(xrow + kc * 32);
            acc = __builtin_amdgcn_mfma_f32_16x16x32_bf16(
                      a, *(const bf16x8*)(bq + kc * 512), acc, 0, 0, 0);
        }
        #pragma unroll
        for (int r = 0; r < 4; ++r)
            cesg[(p0 + wv * 16 + quad * 4 + r) * 16 + m16] = expf(acc[r]);
    }

    // V = X . Wv : kc-outer, 4 nt x 4 m accumulators (all static-indexed)
    floatx4 acc[4][4];                    // [m][local nt]
    #pragma unroll
    for (int m = 0; m < 4; ++m)
        #pragma unroll
        for (int ln = 0; ln < 4; ++ln)
            acc[m][ln] = (floatx4){0.f, 0.f, 0.f, 0.f};

    const short* bvw = Wvh + (4 * wv) * 4096 + lane * 8;
    #pragma unroll
    for (int kc = 0; kc < 8; ++kc) {
        bf16x8 B0 = *(const bf16x8*)(bvw + 0 * 4096 + kc * 512);
        bf16x8 B1 = *(const bf16x8*)(bvw + 1 * 4096 + kc * 512);
        bf16x8 B2 = *(const bf16x8*)(bvw + 2 * 4096 + kc * 512);
        bf16x8 B3 = *(const bf16x8*)(bvw + 3 * 4096 + kc * 512);
        #pragma unroll
        for (int m = 0; m < 4; ++m) {
            bf16x8 a = *(const bf16x8*)&XA[(m * 16 + m16) * XROWA + kc * 32 + quad * 8];
            acc[m][0] = __builtin_amdgcn_mfma_f32_16x16x32_bf16(a, B0, acc[m][0], 0, 0, 0);
            acc[m][1] = __builtin_amdgcn_mfma_f32_16x16x32_bf16(a, B1, acc[m][1], 0, 0, 0);
            acc[m][2] = __builtin_amdgcn_mfma_f32_16x16x32_bf16(a, B2, acc[m][2], 0, 0, 0);
            acc[m][3] = __builtin_amdgcn_mfma_f32_16x16x32_bf16(a, B3, acc[m][3], 0, 0, 0);
        }
    }
    __syncthreads();                      // all XA reads complete -> reusable

    // transpose through dead XA: wave writes its 4 nt columns, all 64 rows
    #pragma unroll
    for (int m = 0; m < 4; ++m)
        #pragma unroll
        for (int ln = 0; ln < 4; ++ln)
            #pragma unroll
            for (int r = 0; r < 4; ++r)
                XA[(m * 16 + quad * 4 + r) * XROWA + (4 * wv + ln) * 16 + m16] =
                    f2bf(acc[m][ln][r]);
    __syncthreads();

    // coalesced bf16x8 V stores
    #pragma unroll
    for (int i = 0; i < 8; ++i) {
        int it  = tid + i * 256;
        int row = it >> 5, l = it & 31;
        *(bf16x8*)&V[(p0 + row) * 256 + l * 8] =
            *(const bf16x8*)&XA[row * XROWA + l * 8];
    }
}

// ---------------------------------------------------------------------------
// Kernel B: softmax-stencil + output projection. Block = 16 output pixels
// (half an output row), 512 thr. ces/V read from global (L2/L3-resident).
// LDS 14 KB, 3 barriers -> high occupancy; OOB window taps get weight 0 and
// a clamped (safe) address.  (unchanged from round 9 — verified ~25 us)
// ---------------------------------------------------------------------------
#define OROW 264
__global__ __launch_bounds__(512) void qb_kernel(
    const float* __restrict__ cesg,       // [131072][16]
    const short* __restrict__ V,          // [131072][256] bf16
    const float* __restrict__ rpe_exp,    // [9][16]
    const float* __restrict__ rpe_scale,  // [9][16]
    const short* __restrict__ Bo,         // [65536]
    float* __restrict__ out)              // [32768][256] fp32
{
    __shared__ short out_tr[16 * OROW];   // 8448 B
    __shared__ float wcoefs[8][9][16];    // 4608 B [h][w][op]
    __shared__ float invden[16][16];      // 1024 B  (total 14080)

    int tid  = threadIdx.x;
    int lane = tid & 63, wv = tid >> 6;
    int m16  = lane & 15, quad = lane >> 4;

    int blk0 = blockIdx.x;
    int blk  = ((blk0 & 7) << 8) | (blk0 >> 3);  // XCD-contiguous, bijective
    int b   = blk >> 6;
    int io  = (blk >> 1) & 31;
    int hf  = blk & 1;
    int i0  = io * 2 - 1;
    int jbase = hf * 32 - 1;

    // ---- P2a: invden ----
    if (tid < 256) {
        int op = tid >> 4, g = tid & 15;
        float den = 0.f;
        #pragma unroll
        for (int w = 0; w < 9; ++w) {
            int ky = w / 3, kx = w - ky * 3;
            int ii = i0 + ky, jj = jbase + 2 * op + kx;
            if ((unsigned)ii < 64u && (unsigned)jj < 64u) {
                size_t pix = ((size_t)((b << 6) + ii) << 6) + jj;
                den = fmaf(rpe_exp[w * 16 + g], cesg[pix * 16 + g], den);
            }
        }
        invden[op][g] = 1.0f / den;
    }
    __syncthreads();

    // ---- P2b: wcoefs[h][w][op] (queries q=0/1 merged; 0 when OOB) ----
    for (int it = tid; it < 1152; it += 512) {
        int op = it / 72, r = it - op * 72;
        int w = r >> 3, h = r & 7;
        int ky = w / 3, kx = w - ky * 3;
        int ii = i0 + ky, jj = jbase + 2 * op + kx;
        float v = 0.f;
        if ((unsigned)ii < 64u && (unsigned)jj < 64u) {
            size_t pix = ((size_t)((b << 6) + ii) << 6) + jj;
            v = cesg[pix * 16 + h]     * rpe_scale[w * 16 + h]     * invden[op][h] +
                cesg[pix * 16 + 8 + h] * rpe_scale[w * 16 + 8 + h] * invden[op][8 + h];
        }
        wcoefs[h][w][op] = v;
    }
    __syncthreads();

    // ---- P3: stencil on V (global, coalesced 512B rows) -> out_tr ----
    {
        int op = tid >> 5;                // 0..15
        int nc = tid & 31;                // 8-feature chunk
        int h  = nc >> 2;
        float wcv[9];
        #pragma unroll
        for (int w = 0; w < 9; ++w) wcv[w] = wcoefs[h][w][op];

        float o[8];
        #pragma unroll
        for (int j = 0; j < 8; ++j) o[j] = 0.f;
        #pragma unroll
        for (int w = 0; w < 9; ++w) {
            int ky = w / 3, kx = w - ky * 3;
            int ii = i0 + ky, jj = jbase + 2 * op + kx;
            bool valid = ((unsigned)ii < 64u) && ((unsigned)jj < 64u);
            size_t pix = valid ? (((size_t)((b << 6) + ii) << 6) + jj) : 0;
            bf16x8 vv = *(const bf16x8*)&V[pix * 256 + nc * 8];
            #pragma unroll
            for (int j = 0; j < 8; ++j)
                o[j] = fmaf(wcv[w], bf2f(vv[j]), o[j]);   // wcv==0 when OOB
        }
        bf16x8 ob;
        #pragma unroll
        for (int j = 0; j < 8; ++j) ob[j] = f2bf(o[j]);
        *(bf16x8*)&out_tr[op * OROW + nc * 8] = ob;
    }
    __syncthreads();

    // ---- P5: out = out_tr . Wo (nt pair = wave), write fp32 ----
    {
        floatx4 acc0 = (floatx4){0.f, 0.f, 0.f, 0.f};
        floatx4 acc1 = (floatx4){0.f, 0.f, 0.f, 0.f};
        int nt0 = wv * 2;
        const short* bp = Bo + nt0 * 4096 + lane * 8;
        #pragma unroll
        for (int kc = 0; kc < 8; ++kc) {
            bf16x8 a  = *(const bf16x8*)&out_tr[m16 * OROW + kc * 32 + quad * 8];
            bf16x8 b0 = *(const bf16x8*)(bp + kc * 512);
            bf16x8 b1 = *(const bf16x8*)(bp + 4096 + kc * 512);
            acc0 = __builtin_amdgcn_mfma_f32_16x16x32_bf16(a, b0, acc0, 0, 0, 0);
            acc1 = __builtin_amdgcn_mfma_f32_16x16x32_bf16(a, b1, acc1, 0, 0, 0);
        }
        size_t op0 = (size_t)blk * 16;
        #pragma unroll
        for (int r = 0; r < 4; ++r) {
            out[(op0 + quad * 4 + r) * 256 + nt0 * 16 + m16]       = acc0[r];
            out[(op0 + quad * 4 + r) * 256 + (nt0 + 1) * 16 + m16] = acc1[r];
        }
    }
}

// ---------------------------------------------------------------------------
// workspace layout (floats):
//   [0,144) rpe_exp  [144,288) rpe_scale  [288,2336) Bq
//   [2336,35104) Wvh  [35104,67872) Bo
//   [68608, +16777216) V (64 MiB bf16)   [+16777216, +2097152) ces (8 MiB)
// ---------------------------------------------------------------------------
extern "C" void kernel_launch(void* const* d_in, const int* in_sizes, int n_in,
                              void* d_out, int out_size, void* d_ws, size_t ws_size,
                              hipStream_t stream)
{
    const float* x     = (const float*)d_in[0];
    const float* query = (const float*)d_in[1];
    const float* Wk    = (const float*)d_in[2];
    const float* Wv    = (const float*)d_in[3];
    const float* rpe   = (const float*)d_in[4];
    const float* asw   = (const float*)d_in[5];
    const float* Wo    = (const float*)d_in[6];
    float* out = (float*)d_out;

    float* ws        = (float*)d_ws;
    float* rpe_exp   = ws;
    float* rpe_scale = ws + 144;
    short* Bq        = (short*)(ws + 288);
    short* Wvh       = (short*)(ws + 288 + 2048);
    short* Bo        = (short*)(ws + 288 + 2048 + 32768);
    short* V         = (short*)(ws + 68608);
    float* cesg      = ws + 68608 + 16777216;

    prep_kernel<<<dim3(16), dim3(256), 0, stream>>>(query, Wk, rpe, asw, Wv, Wo,
                                                    rpe_exp, rpe_scale, Bq, Wvh, Bo);
    va_kernel<<<dim3(2048), dim3(256), 0, stream>>>(x, Bq, Wvh, V, cesg);
    qb_kernel<<<dim3(2048), dim3(512), 0, stream>>>(cesg, V, rpe_exp, rpe_scale,
                                                    Bo, out);
}